// Round 12
// baseline (118.443 us; speedup 1.0000x reference)
//
#include <hip/hip_runtime.h>

typedef unsigned short u16;
typedef __bf16 bf16x8 __attribute__((ext_vector_type(8)));
typedef float f32x16 __attribute__((ext_vector_type(16)));
typedef unsigned short u16x8 __attribute__((ext_vector_type(8)));

#define DIM 512
#define EPSV 1e-6f
#define MARGIN 0.2f
#define DEPS2 (512.0f * 1e-6f * 1e-6f)
#define BK 32
#define NSLICE (DIM / BK)   // 16
#define RING 3

#define AS1 __attribute__((address_space(1)))
#define AS3 __attribute__((address_space(3)))

__device__ __forceinline__ u16 f2bf(float f) {
    unsigned int u = __float_as_uint(f);
    unsigned int r = (u + 0x7fffu + ((u >> 16) & 1u)) >> 16;
    return (u16)r;
}

// ---------------- Kernel 1: per-row stats + bf16 convert ----------------
__global__ __launch_bounds__(256) void prep_kernel(
        const float* __restrict__ A, const float* __restrict__ P,
        u16* __restrict__ Abf, float* __restrict__ alpha,
        float* __restrict__ beta, float* __restrict__ dap,
        unsigned int* __restrict__ dan2, int N) {
    int row = blockIdx.x * 4 + (threadIdx.x >> 6);
    int lane = threadIdx.x & 63;
    if (row >= N) return;
    const float* a = A + (size_t)row * DIM + lane * 8;
    const float* p = P + (size_t)row * DIM + lane * 8;
    float4 a0 = *(const float4*)(a);
    float4 a1 = *(const float4*)(a + 4);
    float4 p0 = *(const float4*)(p);
    float4 p1 = *(const float4*)(p + 4);
    float av[8] = {a0.x, a0.y, a0.z, a0.w, a1.x, a1.y, a1.z, a1.w};
    float pv[8] = {p0.x, p0.y, p0.z, p0.w, p1.x, p1.y, p1.z, p1.w};
    float sq = 0.f, s = 0.f, dp = 0.f;
    u16x8 ob;
    #pragma unroll
    for (int e = 0; e < 8; ++e) {
        float x = av[e];
        sq = fmaf(x, x, sq);
        s += x;
        float d = x - pv[e] + EPSV;
        dp = fmaf(d, d, dp);
        ob[e] = f2bf(x);
    }
    *reinterpret_cast<u16x8*>(Abf + (size_t)row * DIM + lane * 8) = ob;
    #pragma unroll
    for (int mask = 32; mask; mask >>= 1) {
        sq += __shfl_xor(sq, mask, 64);
        s  += __shfl_xor(s,  mask, 64);
        dp += __shfl_xor(dp, mask, 64);
    }
    if (lane == 0) {
        alpha[row] = fmaf(2.0f * EPSV, s, sq);
        beta[row]  = fmaf(-2.0f * EPSV, s, sq);
        dap[row]   = sqrtf(dp);
        dan2[row]  = 0x7f800000u;   // +inf
    }
}

// ---------------- Kernel 2: 256x128-tile ring-3 Gram (32x32x16) + row/col min ----------------
// r7 chassis (verified 54 us): staging w/ inverse granule rotation, ring-3,
// counted vmcnt(3)/slice, b>=2a triangular cover.
// THIS ROUND: 32x32x16 MFMA path (r6-verified frag + epilogue) -- per wave per
// slice 8 ds_read_b128 + 8 MFMA (vs 12 + 16 for 16x16x32): LDS issue -33%,
// MFMA issue -50%, same FLOPs. Reads stay 2-way-aliased per 16-lane phase (free).
__global__ __launch_bounds__(512, 4) void gemm_min_kernel(
        const u16* __restrict__ Abf, const float* __restrict__ alpha,
        const float* __restrict__ beta, unsigned int* __restrict__ dan2, int N) {

    __shared__ u16 lds[RING][12288];   // 72 KiB: per slot A=8192 u16, B=4096 u16

    // XCD-chunked bijective swizzle: 1056 = 8 * 132
    int orig = blockIdx.x;
    int v = (orig & 7) * 132 + (orig >> 3);

    // decode v -> (a, btile): offset(a) = a*(65-a), btile = 2a + (v - offset(a))
    int a = (int)((65.0f - sqrtf(4225.0f - 4.0f * (float)v)) * 0.5f);
    while ((a + 1) * (65 - (a + 1)) <= v) ++a;
    while (a * (65 - a) > v) --a;
    int btile = 2 * a + (v - a * (65 - a));
    int ibase = a << 8, jbase = btile << 7;

    int tid = threadIdx.x;
    int wave = tid >> 6, lane = tid & 63;
    int wr = wave >> 1, wc = wave & 1;      // 4 x 2 wave grid, 64x64 per wave
    int h = lane >> 5, c31 = lane & 31;

    // staging (r7-verified): lane -> (row = base + lane>>2, slot p = lane&3);
    // source granule = inverse rotation
    int srow = lane >> 2;
    int gsrc = ((lane & 3) - ((lane >> 3) & 3)) & 3;
    const u16* pA0 = Abf + (size_t)(ibase + wave * 32 + srow) * DIM + gsrc * 8;
    const u16* pA1 = Abf + (size_t)(ibase + wave * 32 + 16 + srow) * DIM + gsrc * 8;
    const u16* pB  = Abf + (size_t)(jbase + wave * 16 + srow) * DIM + gsrc * 8;

    // ds_read offsets (u16) for k16-step s=0 (logical granule G = h):
    // row r slot p=(G+((r>>1)&3))&3 at r*32 + p*8.  s=1: G+=2 -> p^=2 -> off^=16.
    int aOff[2], bOff[2];
    #pragma unroll
    for (int mf = 0; mf < 2; ++mf) {
        int r = wr * 64 + mf * 32 + c31;
        aOff[mf] = r * 32 + (((h + (r >> 1)) & 3) << 3);
    }
    #pragma unroll
    for (int nf = 0; nf < 2; ++nf) {
        int c = wc * 64 + nf * 32 + c31;
        bOff[nf] = 8192 + c * 32 + (((h + (c >> 1)) & 3) << 3);
    }

    f32x16 acc[2][2];
    #pragma unroll
    for (int mf = 0; mf < 2; ++mf)
        #pragma unroll
        for (int nf = 0; nf < 2; ++nf)
            #pragma unroll
            for (int e = 0; e < 16; ++e) acc[mf][nf][e] = 0.f;

    auto stage = [&](int t, int slot) {
        u16* base = &lds[slot][0];
        __builtin_amdgcn_global_load_lds((const AS1 void*)(pA0 + t * BK),
            (AS3 void*)(base + wave * 1024), 16, 0, 0);
        __builtin_amdgcn_global_load_lds((const AS1 void*)(pA1 + t * BK),
            (AS3 void*)(base + wave * 1024 + 512), 16, 0, 0);
        __builtin_amdgcn_global_load_lds((const AS1 void*)(pB + t * BK),
            (AS3 void*)(base + 8192 + wave * 512), 16, 0, 0);
    };

    // prologue: stage slices 0,1; certify slice 0 (slice 1's 3 loads in flight)
    stage(0, 0);
    stage(1, 1);
    asm volatile("s_waitcnt vmcnt(3)" ::: "memory");
    __builtin_amdgcn_s_barrier();
    __builtin_amdgcn_sched_barrier(0);

    #pragma unroll
    for (int t = 0; t < NSLICE; ++t) {
        const int slot = t % RING;
        if (t + 2 < NSLICE) stage(t + 2, (t + 2) % RING);

        const u16* base = &lds[slot][0];
        bf16x8 af0[2], bf0[2], af1[2], bf1[2];
        #pragma unroll
        for (int mf = 0; mf < 2; ++mf) {
            af0[mf] = *reinterpret_cast<const bf16x8*>(base + aOff[mf]);
            af1[mf] = *reinterpret_cast<const bf16x8*>(base + (aOff[mf] ^ 16));
        }
        #pragma unroll
        for (int nf = 0; nf < 2; ++nf) {
            bf0[nf] = *reinterpret_cast<const bf16x8*>(base + bOff[nf]);
            bf1[nf] = *reinterpret_cast<const bf16x8*>(base + (bOff[nf] ^ 16));
        }

        __builtin_amdgcn_s_setprio(1);
        acc[0][0] = __builtin_amdgcn_mfma_f32_32x32x16_bf16(af0[0], bf0[0], acc[0][0], 0, 0, 0);
        acc[0][1] = __builtin_amdgcn_mfma_f32_32x32x16_bf16(af0[0], bf0[1], acc[0][1], 0, 0, 0);
        acc[1][0] = __builtin_amdgcn_mfma_f32_32x32x16_bf16(af0[1], bf0[0], acc[1][0], 0, 0, 0);
        acc[1][1] = __builtin_amdgcn_mfma_f32_32x32x16_bf16(af0[1], bf0[1], acc[1][1], 0, 0, 0);
        acc[0][0] = __builtin_amdgcn_mfma_f32_32x32x16_bf16(af1[0], bf1[0], acc[0][0], 0, 0, 0);
        acc[0][1] = __builtin_amdgcn_mfma_f32_32x32x16_bf16(af1[0], bf1[1], acc[0][1], 0, 0, 0);
        acc[1][0] = __builtin_amdgcn_mfma_f32_32x32x16_bf16(af1[1], bf1[0], acc[1][0], 0, 0, 0);
        acc[1][1] = __builtin_amdgcn_mfma_f32_32x32x16_bf16(af1[1], bf1[1], acc[1][1], 0, 0, 0);
        __builtin_amdgcn_s_setprio(0);

        if (t + 1 < NSLICE) {
            if (t + 2 < NSLICE) { asm volatile("s_waitcnt vmcnt(3)" ::: "memory"); }
            else                { asm volatile("s_waitcnt vmcnt(0)" ::: "memory"); }
            __builtin_amdgcn_s_barrier();
            __builtin_amdgcn_sched_barrier(0);
        }
    }

    const float INF = __builtin_inff();

    // ---- row-side (r6-verified): rows I, min over this wave's 64 cols ----
    // C/D 32x32 layout: col = lane&31, row = (reg&3) + 8*(reg>>2) + 4*(lane>>5)
    float bb0 = beta[jbase + wc * 64 + c31];
    float bb1 = beta[jbase + wc * 64 + 32 + c31];
    int gcol0 = jbase + wc * 64 + c31;
    int gcol1 = gcol0 + 32;

    #pragma unroll
    for (int mf = 0; mf < 2; ++mf) {
        #pragma unroll
        for (int reg = 0; reg < 16; ++reg) {
            int rl = (reg & 3) + 8 * (reg >> 2);
            int grow = ibase + wr * 64 + mf * 32 + rl + 4 * h;
            float v0 = fmaf(-2.f, acc[mf][0][reg], bb0);
            float v1 = fmaf(-2.f, acc[mf][1][reg], bb1);
            if (grow == gcol0) v0 = INF;
            if (grow == gcol1) v1 = INF;
            float w = fminf(v0, v1);
            w = fminf(w, __shfl_xor(w, 1, 64));
            w = fminf(w, __shfl_xor(w, 2, 64));
            w = fminf(w, __shfl_xor(w, 4, 64));
            w = fminf(w, __shfl_xor(w, 8, 64));
            w = fminf(w, __shfl_xor(w, 16, 64));
            if (c31 == 0) {
                float d2 = fmaxf(alpha[grow] + DEPS2 + w, 0.f);
                atomicMin(dan2 + grow, __float_as_uint(d2));
            }
        }
    }

    // ---- col-side (r6-verified): this wave's 64 cols, min over its 64 rows ----
    {
        float b_w = beta[ibase + wr * 64 + lane];   // this wave's 64 rows
        float cm0 = INF, cm1 = INF;
        #pragma unroll
        for (int mf = 0; mf < 2; ++mf) {
            #pragma unroll
            for (int reg = 0; reg < 16; ++reg) {
                int rl = (reg & 3) + 8 * (reg >> 2);
                int idx = mf * 32 + rl + 4 * h;          // 0..63 within wave's rows
                float bv = __shfl(b_w, idx, 64);
                int rowg = ibase + wr * 64 + idx;
                float c0 = fmaf(-2.f, acc[mf][0][reg], bv);
                float c1 = fmaf(-2.f, acc[mf][1][reg], bv);
                if (rowg == gcol0) c0 = INF;
                if (rowg == gcol1) c1 = INF;
                cm0 = fminf(cm0, c0);
                cm1 = fminf(cm1, c1);
            }
        }
        cm0 = fminf(cm0, __shfl_xor(cm0, 32, 64));
        cm1 = fminf(cm1, __shfl_xor(cm1, 32, 64));
        if (lane < 32) {
            int gc0 = jbase + wc * 64 + lane;
            int gc1 = gc0 + 32;
            float d20 = fmaxf(alpha[gc0] + DEPS2 + cm0, 0.f);
            float d21 = fmaxf(alpha[gc1] + DEPS2 + cm1, 0.f);
            atomicMin(dan2 + gc0, __float_as_uint(d20));
            atomicMin(dan2 + gc1, __float_as_uint(d21));
        }
    }
}

// ---------------- Kernel 3: final loss reduction ----------------
__global__ __launch_bounds__(1024) void finalize_kernel(
        const float* __restrict__ dap, const unsigned int* __restrict__ dan2,
        float* __restrict__ out, int N) {
    __shared__ float red[16];
    float sum = 0.f;
    for (int i = threadIdx.x; i < N; i += 1024) {
        float dan = sqrtf(__uint_as_float(dan2[i]));
        float v = dap[i] - dan + MARGIN;
        sum += fmaxf(v, 0.f);
    }
    #pragma unroll
    for (int mask = 32; mask; mask >>= 1) sum += __shfl_xor(sum, mask, 64);
    int lane = threadIdx.x & 63, w = threadIdx.x >> 6;
    if (lane == 0) red[w] = sum;
    __syncthreads();
    if (threadIdx.x == 0) {
        float tot = 0.f;
        #pragma unroll
        for (int k = 0; k < 16; ++k) tot += red[k];
        out[0] = tot / (float)N;
    }
}

extern "C" void kernel_launch(void* const* d_in, const int* in_sizes, int n_in,
                              void* d_out, int out_size, void* d_ws, size_t ws_size,
                              hipStream_t stream) {
    const float* anchor   = (const float*)d_in[0];
    const float* positive = (const float*)d_in[1];
    int N = in_sizes[0] / DIM;   // 8192
    float* out = (float*)d_out;

    char* ws = (char*)d_ws;
    float* alpha = (float*)ws;
    float* beta  = alpha + N;
    float* dap   = beta + N;
    unsigned int* dan2 = (unsigned int*)(dap + N);
    u16* Abf = (u16*)(dan2 + N);   // N*DIM bf16 = 8.4 MB

    prep_kernel<<<N / 4, 256, 0, stream>>>(anchor, positive, Abf, alpha, beta, dap, dan2, N);
    // kept tiles: (a, b) with b >= 2a; count = sum_a (64-2a) = 1056 = 8*132
    gemm_min_kernel<<<1056, 512, 0, stream>>>(Abf, alpha, beta, dan2, N);
    finalize_kernel<<<1, 1024, 0, stream>>>(dap, dan2, out, N);
}

// Round 13
// 55.162 us; speedup vs baseline: 2.1472x; 2.1472x over previous
//
#include <hip/hip_runtime.h>

typedef unsigned char u8;
typedef float f32x4 __attribute__((ext_vector_type(4)));
typedef unsigned long ulx2 __attribute__((ext_vector_type(2)));
typedef unsigned int uix2 __attribute__((ext_vector_type(2)));

#define DIM 512
#define EPSV 1e-6f
#define MARGIN 0.2f
#define DEPS2 (512.0f * 1e-6f * 1e-6f)
#define BK 64
#define NSLICE (DIM / BK)   // 8
#define RING 3

#define AS1 __attribute__((address_space(1)))
#define AS3 __attribute__((address_space(3)))

// ---------------- Kernel 1: per-row stats + fp8 e4m3 convert (k-permuted) ----------------
// Stored layout per row (512 B): for k-block kb (64 elems), granule j (16 B) at
// byte kb*64 + j*16 holds fp8[k = kb*64 + j*8 .. +7] (lo, 8 B) || fp8[kb*64 + 32
// + j*8 .. +7] (hi, 8 B) -- so one b128 LDS read yields BOTH K=32 MFMA frags.
__global__ __launch_bounds__(256) void prep_kernel(
        const float* __restrict__ A, const float* __restrict__ P,
        u8* __restrict__ Aq, float* __restrict__ alpha,
        float* __restrict__ beta, float* __restrict__ dap,
        unsigned int* __restrict__ dan2, int N) {
    int row = blockIdx.x * 4 + (threadIdx.x >> 6);
    int lane = threadIdx.x & 63;
    if (row >= N) return;
    const float* a = A + (size_t)row * DIM + lane * 8;
    const float* p = P + (size_t)row * DIM + lane * 8;
    float4 a0 = *(const float4*)(a);
    float4 a1 = *(const float4*)(a + 4);
    float4 p0 = *(const float4*)(p);
    float4 p1 = *(const float4*)(p + 4);
    float av[8] = {a0.x, a0.y, a0.z, a0.w, a1.x, a1.y, a1.z, a1.w};
    float pv[8] = {p0.x, p0.y, p0.z, p0.w, p1.x, p1.y, p1.z, p1.w};
    float sq = 0.f, s = 0.f, dp = 0.f;
    #pragma unroll
    for (int e = 0; e < 8; ++e) {
        float x = av[e];
        sq = fmaf(x, x, sq);
        s += x;
        float d = x - pv[e] + EPSV;
        dp = fmaf(d, d, dp);
    }
    // pack 8 fp32 -> 8 fp8 e4m3 (OCP), bytes ascending in k
    unsigned w0 = __builtin_amdgcn_cvt_pk_fp8_f32(av[0], av[1], 0, false);
    w0 = __builtin_amdgcn_cvt_pk_fp8_f32(av[2], av[3], w0, true);
    unsigned w1 = __builtin_amdgcn_cvt_pk_fp8_f32(av[4], av[5], 0, false);
    w1 = __builtin_amdgcn_cvt_pk_fp8_f32(av[6], av[7], w1, true);
    // this thread covers k = lane*8..+7: kb = lane>>3, chunk c = lane&7
    // dest: lo-chunks (c<4) at granule j=c byte 0; hi-chunks at j=c-4 byte 8
    int kb = lane >> 3, c = lane & 7;
    int dst = kb * 64 + (c & 3) * 16 + (c >> 2) * 8;
    uix2 w = {w0, w1};
    *reinterpret_cast<uix2*>(Aq + (size_t)row * DIM + dst) = w;

    #pragma unroll
    for (int mask = 32; mask; mask >>= 1) {
        sq += __shfl_xor(sq, mask, 64);
        s  += __shfl_xor(s,  mask, 64);
        dp += __shfl_xor(dp, mask, 64);
    }
    if (lane == 0) {
        alpha[row] = fmaf(2.0f * EPSV, s, sq);
        beta[row]  = fmaf(-2.0f * EPSV, s, sq);
        dap[row]   = sqrtf(dp);
        dan2[row]  = 0x7f800000u;   // +inf
    }
}

// ---------------- Kernel 2: 256x128-tile ring-3 fp8 Gram + row/col min ----------------
// r7 chassis with BYTE-IDENTICAL LDS geometry (row=64B, 4x16B granules, rotation
// swizzle (g+(row>>1))&3, inverse-rotated staging -- measured 0 conflicts), but
// fp8 K=64 slices: 8 slices, 8 b128 reads + 32 fp8 MFMAs per wave-slice.
__global__ __launch_bounds__(512, 4) void gemm_min_kernel(
        const u8* __restrict__ Aq, const float* __restrict__ alpha,
        const float* __restrict__ beta, unsigned int* __restrict__ dan2, int N) {

    __shared__ u8 lds[RING][24576];   // 72 KiB: per slot A=16384 B, B=8192 B

    // XCD-chunked bijective swizzle: 1056 = 8 * 132
    int orig = blockIdx.x;
    int v = (orig & 7) * 132 + (orig >> 3);

    // decode v -> (a, btile): offset(a) = a*(65-a), btile = 2a + (v - offset(a))
    int a = (int)((65.0f - sqrtf(4225.0f - 4.0f * (float)v)) * 0.5f);
    while ((a + 1) * (65 - (a + 1)) <= v) ++a;
    while (a * (65 - a) > v) --a;
    int btile = 2 * a + (v - a * (65 - a));
    int ibase = a << 8, jbase = btile << 7;

    int tid = threadIdx.x;
    int wave = tid >> 6, lane = tid & 63;
    int wr = wave >> 1, wc = wave & 1;      // 4 x 2 wave grid, 64x64 per wave
    int g = lane >> 4, tl = lane & 15;

    // staging (r7-verified involution): lane -> (row = base + lane>>2, slot p = lane&3);
    // source granule = inverse rotation (p - (row>>1))&3, row>>1 == lane>>3
    int srow = lane >> 2;
    int gsrc = ((lane & 3) - ((lane >> 3) & 3)) & 3;
    const u8* pA0 = Aq + (size_t)(ibase + wave * 32 + srow) * DIM + gsrc * 16;
    const u8* pA1 = Aq + (size_t)(ibase + wave * 32 + 16 + srow) * DIM + gsrc * 16;
    const u8* pB  = Aq + (size_t)(jbase + wave * 16 + srow) * DIM + gsrc * 16;

    // ds_read byte offsets: row r slot s at r*64 + s*16, s = (g + ((r>>1)&3))&3
    // (r>>1)&3 reduces to (tl>>1)&3 for our row bases (multiples of 8)
    int swz = (g + ((tl >> 1) & 3)) & 3;
    int aOff[4], bOff[4];
    #pragma unroll
    for (int mf = 0; mf < 4; ++mf)
        aOff[mf] = (wr * 64 + mf * 16 + tl) * 64 + swz * 16;
    #pragma unroll
    for (int nf = 0; nf < 4; ++nf)
        bOff[nf] = 16384 + (wc * 64 + nf * 16 + tl) * 64 + swz * 16;

    f32x4 acc[4][4];
    f32x4 zero = {0.f, 0.f, 0.f, 0.f};
    #pragma unroll
    for (int mf = 0; mf < 4; ++mf)
        #pragma unroll
        for (int nf = 0; nf < 4; ++nf) acc[mf][nf] = zero;

    auto stage = [&](int t, int slot) {
        u8* base = &lds[slot][0];
        __builtin_amdgcn_global_load_lds((const AS1 void*)(pA0 + t * 64),
            (AS3 void*)(base + wave * 2048), 16, 0, 0);
        __builtin_amdgcn_global_load_lds((const AS1 void*)(pA1 + t * 64),
            (AS3 void*)(base + wave * 2048 + 1024), 16, 0, 0);
        __builtin_amdgcn_global_load_lds((const AS1 void*)(pB + t * 64),
            (AS3 void*)(base + 16384 + wave * 1024), 16, 0, 0);
    };

    // prologue: stage slices 0,1; certify slice 0 (slice 1's 3 loads in flight)
    stage(0, 0);
    stage(1, 1);
    asm volatile("s_waitcnt vmcnt(3)" ::: "memory");
    __builtin_amdgcn_s_barrier();
    __builtin_amdgcn_sched_barrier(0);

    #pragma unroll
    for (int t = 0; t < NSLICE; ++t) {
        const int slot = t % RING;
        if (t + 2 < NSLICE) stage(t + 2, (t + 2) % RING);

        const u8* base = &lds[slot][0];
        ulx2 av4[4], bv4[4];
        #pragma unroll
        for (int mf = 0; mf < 4; ++mf)
            av4[mf] = *reinterpret_cast<const ulx2*>(base + aOff[mf]);
        #pragma unroll
        for (int nf = 0; nf < 4; ++nf)
            bv4[nf] = *reinterpret_cast<const ulx2*>(base + bOff[nf]);

        __builtin_amdgcn_s_setprio(1);
        #pragma unroll
        for (int mf = 0; mf < 4; ++mf)
            #pragma unroll
            for (int nf = 0; nf < 4; ++nf)
                acc[mf][nf] = __builtin_amdgcn_mfma_f32_16x16x32_fp8_fp8(
                    (long)av4[mf][0], (long)bv4[nf][0], acc[mf][nf], 0, 0, 0);
        #pragma unroll
        for (int mf = 0; mf < 4; ++mf)
            #pragma unroll
            for (int nf = 0; nf < 4; ++nf)
                acc[mf][nf] = __builtin_amdgcn_mfma_f32_16x16x32_fp8_fp8(
                    (long)av4[mf][1], (long)bv4[nf][1], acc[mf][nf], 0, 0, 0);
        __builtin_amdgcn_s_setprio(0);

        if (t + 1 < NSLICE) {
            if (t + 2 < NSLICE) { asm volatile("s_waitcnt vmcnt(3)" ::: "memory"); }
            else                { asm volatile("s_waitcnt vmcnt(0)" ::: "memory"); }
            __builtin_amdgcn_s_barrier();
            __builtin_amdgcn_sched_barrier(0);
        }
    }

    const float INF = __builtin_inff();

    // ---- row-side: rows I, min over this wave's 64 cols (r7-verified) ----
    // C/D 16x16 layout: col = lane&15, row = (lane>>4)*4 + reg (dtype-independent)
    float bb[4];
    #pragma unroll
    for (int nf = 0; nf < 4; ++nf) bb[nf] = beta[jbase + wc * 64 + nf * 16 + tl];

    #pragma unroll
    for (int mf = 0; mf < 4; ++mf) {
        int grow0 = ibase + wr * 64 + mf * 16 + g * 4;
        float mn0 = INF, mn1 = INF, mn2 = INF, mn3 = INF;
        #pragma unroll
        for (int nf = 0; nf < 4; ++nf) {
            int gcol = jbase + wc * 64 + nf * 16 + tl;
            float c0 = fmaf(-2.f, acc[mf][nf][0], bb[nf]);
            float c1 = fmaf(-2.f, acc[mf][nf][1], bb[nf]);
            float c2 = fmaf(-2.f, acc[mf][nf][2], bb[nf]);
            float c3 = fmaf(-2.f, acc[mf][nf][3], bb[nf]);
            if (grow0 + 0 == gcol) c0 = INF;
            if (grow0 + 1 == gcol) c1 = INF;
            if (grow0 + 2 == gcol) c2 = INF;
            if (grow0 + 3 == gcol) c3 = INF;
            mn0 = fminf(mn0, c0);
            mn1 = fminf(mn1, c1);
            mn2 = fminf(mn2, c2);
            mn3 = fminf(mn3, c3);
        }
        #pragma unroll
        for (int mask = 1; mask < 16; mask <<= 1) {
            mn0 = fminf(mn0, __shfl_xor(mn0, mask, 64));
            mn1 = fminf(mn1, __shfl_xor(mn1, mask, 64));
            mn2 = fminf(mn2, __shfl_xor(mn2, mask, 64));
            mn3 = fminf(mn3, __shfl_xor(mn3, mask, 64));
        }
        if (tl == 0) {
            float d20 = fmaxf(alpha[grow0 + 0] + DEPS2 + mn0, 0.f);
            float d21 = fmaxf(alpha[grow0 + 1] + DEPS2 + mn1, 0.f);
            float d22 = fmaxf(alpha[grow0 + 2] + DEPS2 + mn2, 0.f);
            float d23 = fmaxf(alpha[grow0 + 3] + DEPS2 + mn3, 0.f);
            atomicMin(dan2 + grow0 + 0, __float_as_uint(d20));
            atomicMin(dan2 + grow0 + 1, __float_as_uint(d21));
            atomicMin(dan2 + grow0 + 2, __float_as_uint(d22));
            atomicMin(dan2 + grow0 + 3, __float_as_uint(d23));
        }
    }

    // ---- col-side: this wave's 64 cols, min over the wave's 64 rows (diag masked) ----
    #pragma unroll
    for (int nf = 0; nf < 4; ++nf) {
        int gcol = jbase + wc * 64 + nf * 16 + tl;
        float cm = INF;
        #pragma unroll
        for (int mf = 0; mf < 4; ++mf) {
            int grow0 = ibase + wr * 64 + mf * 16 + g * 4;
            #pragma unroll
            for (int e = 0; e < 4; ++e) {
                int rowg = grow0 + e;
                float c = fmaf(-2.f, acc[mf][nf][e], beta[rowg]);
                if (rowg == gcol) c = INF;
                cm = fminf(cm, c);
            }
        }
        cm = fminf(cm, __shfl_xor(cm, 16, 64));
        cm = fminf(cm, __shfl_xor(cm, 32, 64));
        if (g == 0) {
            float d2 = fmaxf(alpha[gcol] + DEPS2 + cm, 0.f);
            atomicMin(dan2 + gcol, __float_as_uint(d2));
        }
    }
}

// ---------------- Kernel 3: final loss reduction ----------------
__global__ __launch_bounds__(1024) void finalize_kernel(
        const float* __restrict__ dap, const unsigned int* __restrict__ dan2,
        float* __restrict__ out, int N) {
    __shared__ float red[16];
    float sum = 0.f;
    for (int i = threadIdx.x; i < N; i += 1024) {
        float dan = sqrtf(__uint_as_float(dan2[i]));
        float v = dap[i] - dan + MARGIN;
        sum += fmaxf(v, 0.f);
    }
    #pragma unroll
    for (int mask = 32; mask; mask >>= 1) sum += __shfl_xor(sum, mask, 64);
    int lane = threadIdx.x & 63, w = threadIdx.x >> 6;
    if (lane == 0) red[w] = sum;
    __syncthreads();
    if (threadIdx.x == 0) {
        float tot = 0.f;
        #pragma unroll
        for (int k = 0; k < 16; ++k) tot += red[k];
        out[0] = tot / (float)N;
    }
}

extern "C" void kernel_launch(void* const* d_in, const int* in_sizes, int n_in,
                              void* d_out, int out_size, void* d_ws, size_t ws_size,
                              hipStream_t stream) {
    const float* anchor   = (const float*)d_in[0];
    const float* positive = (const float*)d_in[1];
    int N = in_sizes[0] / DIM;   // 8192
    float* out = (float*)d_out;

    char* ws = (char*)d_ws;
    float* alpha = (float*)ws;
    float* beta  = alpha + N;
    float* dap   = beta + N;
    unsigned int* dan2 = (unsigned int*)(dap + N);
    u8* Aq = (u8*)(dan2 + N);   // N*DIM fp8 = 4.2 MB, k-permuted layout

    prep_kernel<<<N / 4, 256, 0, stream>>>(anchor, positive, Aq, alpha, beta, dap, dan2, N);
    // kept tiles: (a, b) with b >= 2a; count = sum_a (64-2a) = 1056 = 8*132
    gemm_min_kernel<<<1056, 512, 0, stream>>>(Aq, alpha, beta, dan2, N);
    finalize_kernel<<<1, 1024, 0, stream>>>(dap, dan2, out, N);
}